// Round 5
// baseline (221.766 us; speedup 1.0000x reference)
//
#include <hip/hip_runtime.h>

typedef unsigned short ushort_t;
typedef unsigned int uint_t;

#define B_ 8192
#define C_ 1000
#define CP_ 1024   /* padded classes */
#define D_ 2048
#define BK_ 32
#define NT_ (D_ / BK_)   /* 64 K-steps */

typedef short bf16x8 __attribute__((ext_vector_type(8)));
typedef float f32x4 __attribute__((ext_vector_type(4)));

typedef const __attribute__((address_space(1))) void* as1_cvp;
typedef __attribute__((address_space(3))) void* as3_vp;
#define GLOAD16(gp, lp) __builtin_amdgcn_global_load_lds((as1_cvp)(gp), (as3_vp)(lp), 16, 0, 0)

__device__ __forceinline__ ushort_t f2bf(float f) {
    uint_t x = __float_as_uint(f);
    uint_t r = (x + 0x7fffu + ((x >> 16) & 1u)) >> 16;
    return (ushort_t)r;
}

__device__ __forceinline__ float waveReduce(float v) {
#pragma unroll
    for (int o = 32; o; o >>= 1) v += __shfl_xor(v, o, 64);
    return v;
}

// ---- prep_all: ONE dispatch for all preprocessing.
//  blocks [0,1024):    mu-path: cast mu -> mub (bf16, 1024 rows padded), musq;
//                      also zeros row_sumexp (8 rows/block) and sS (block 0).
//  blocks [1024,9216): z-path (r = blk-1024): label scan of one-hot y, cast z -> zb,
//                      zsq[r], EXACT f32 zz[r,label] (self-computes ||mu_L||^2).
__global__ __launch_bounds__(256) void prep_all(const float* __restrict__ z,
                                                const float* __restrict__ mu,
                                                const float* __restrict__ y,
                                                ushort_t* __restrict__ zb,
                                                ushort_t* __restrict__ mub,
                                                float* __restrict__ musq,
                                                float* __restrict__ zsq,
                                                float* __restrict__ zzlab,
                                                float* __restrict__ rs,
                                                float* __restrict__ sS) {
    const int t = threadIdx.x;
    __shared__ float sb[3][4];
    __shared__ int slab;

    if (blockIdx.x < CP_) {
        const int c = blockIdx.x;
        // fold the old hipMemsetAsync: zero row_sumexp + sS before gemm (stream-ordered)
        if (t < 8) rs[c * 8 + t] = 0.f;
        if (c == 0 && t == 0) *sS = 0.f;
        if (c < C_) {
            const float4* mr = (const float4*)(mu + (size_t)c * D_);
            float4 a = mr[t * 2];
            float4 b = mr[t * 2 + 1];
            float vals[8] = {a.x, a.y, a.z, a.w, b.x, b.y, b.z, b.w};
            ushort_t u[8];
            float ss = 0.f;
#pragma unroll
            for (int i = 0; i < 8; i++) { ss += vals[i] * vals[i]; u[i] = f2bf(vals[i]); }
            *(uint4*)(mub + (size_t)c * D_ + t * 8) = *(const uint4*)u;
            ss = waveReduce(ss);
            if ((t & 63) == 0) sb[0][t >> 6] = ss;
            __syncthreads();
            if (t == 0) musq[c] = sb[0][0] + sb[0][1] + sb[0][2] + sb[0][3];
        } else {
            uint4 zero4 = {0, 0, 0, 0};
            *(uint4*)(mub + (size_t)c * D_ + t * 8) = zero4;
            if (t == 0) musq[c] = 1e30f;  // exp(S - 0.5e30) == 0 -> pads vanish from LSE
        }
        return;
    }

    const int r = blockIdx.x - CP_;
    // label scan: one float4 of the one-hot row per thread (250 used)
    if (t < C_ / 4) {
        float4 v = ((const float4*)(y + (size_t)r * C_))[t];
        int idx = -1;
        if (v.x > 0.5f) idx = t * 4 + 0;
        if (v.y > 0.5f) idx = t * 4 + 1;
        if (v.z > 0.5f) idx = t * 4 + 2;
        if (v.w > 0.5f) idx = t * 4 + 3;
        if (idx >= 0) slab = idx;  // exactly one thread writes
    }
    __syncthreads();
    const int L = slab;
    const float4* zr = (const float4*)(z + (size_t)r * D_);
    const float4* mr = (const float4*)(mu + (size_t)L * D_);
    float4 a = zr[t * 2];
    float4 b = zr[t * 2 + 1];
    float4 ma = mr[t * 2];
    float4 mb = mr[t * 2 + 1];
    float vals[8] = {a.x, a.y, a.z, a.w, b.x, b.y, b.z, b.w};
    float mv[8] = {ma.x, ma.y, ma.z, ma.w, mb.x, mb.y, mb.z, mb.w};
    ushort_t u[8];
    float ss = 0.f, dot = 0.f, msq = 0.f;
#pragma unroll
    for (int i = 0; i < 8; i++) {
        ss += vals[i] * vals[i];
        dot += vals[i] * mv[i];
        msq += mv[i] * mv[i];
        u[i] = f2bf(vals[i]);
    }
    *(uint4*)(zb + (size_t)r * D_ + t * 8) = *(const uint4*)u;
    ss = waveReduce(ss);
    dot = waveReduce(dot);
    msq = waveReduce(msq);
    if ((t & 63) == 0) { sb[0][t >> 6] = ss; sb[1][t >> 6] = dot; sb[2][t >> 6] = msq; }
    __syncthreads();
    if (t == 0) {
        float SS = sb[0][0] + sb[0][1] + sb[0][2] + sb[0][3];
        float DT = sb[1][0] + sb[1][1] + sb[1][2] + sb[1][3];
        float MQ = sb[2][0] + sb[2][1] + sb[2][2] + sb[2][3];
        zsq[r] = SS;
        zzlab[r] = SS + MQ - 2.f * DT;
    }
}

// ---- gemm_lse: 64x64 tile, BK=32, ONE WAVE PER BLOCK (no barriers at all),
//      dbuf LDS + counted s_waitcnt vmcnt(8) (loads stay in flight across compute,
//      AITER-style; never drains to 0 in the loop). 2048 independent self-paced
//      waves -> 8 blocks/CU, stalls covered by TLP instead of barrier convoys.
//      Fused epilogue: row_sumexp += sum_c exp(S - 0.5*musq); sS += sum_{c<1000} S.
__global__ __launch_bounds__(64, 2) void gemm_lse(const ushort_t* __restrict__ zb,
                                                  const ushort_t* __restrict__ mub,
                                                  const float* __restrict__ musq,
                                                  float* __restrict__ row_sumexp,
                                                  float* __restrict__ sS) {
    __shared__ ushort_t smA[2][64 * BK_];   // 2 x 4KB
    __shared__ ushort_t smB[2][64 * BK_];   // 2 x 4KB   (16KB total)
    const int lane = threadIdx.x;           // 0..63
    const int l15 = lane & 15;
    const int g = lane >> 4;

    // XCD-aware bijective remap: XCD owns 16 contiguous br panels (A 4MB) + all B (4MB).
    const int f = blockIdx.x;            // 0..2047
    const int xcd = f & 7;
    const int i = f >> 3;                // 0..255
    const int br = xcd * 16 + (i >> 4);  // 0..127
    const int bc = i & 15;               // 0..15

    f32x4 acc[4][4];
#pragma unroll
    for (int m = 0; m < 4; m++)
#pragma unroll
        for (int n = 0; n < 4; n++)
#pragma unroll
            for (int j = 0; j < 4; j++) acc[m][n][j] = 0.f;

    const ushort_t* gA = zb + (size_t)br * 64 * D_;
    const ushort_t* gB = mub + (size_t)bc * 64 * D_;

    // Staging map (per 4KB tile = 4 gload16): ldi = it*64+lane; row = ldi>>2,
    // dest slot' = ldi&3 (linear LDS dest = wave-uniform base + lane*16, m104-safe);
    // global source slot = slot' ^ ((row>>1)&3)  [rule 21: inverse-swizzled source].
    int st_r[4], st_s[4];
#pragma unroll
    for (int it = 0; it < 4; it++) {
        int ldi = it * 64 + lane;
        st_r[it] = ldi >> 2;
        st_s[it] = (ldi & 3) ^ ((st_r[it] >> 1) & 3);
    }

#define STAGE(sel, kk)                                                                 \
    {                                                                                  \
        _Pragma("unroll") for (int it = 0; it < 4; it++) {                             \
            GLOAD16(gA + (size_t)st_r[it] * D_ + (kk) + st_s[it] * 8,                  \
                    &smA[sel][(it * 64 + lane) * 8]);                                  \
            GLOAD16(gB + (size_t)st_r[it] * D_ + (kk) + st_s[it] * 8,                  \
                    &smB[sel][(it * 64 + lane) * 8]);                                  \
        }                                                                              \
    }

    // read slot = g ^ ((r>>1)&3): banks spread so only row-pairs 8 apart alias
    // -> 2 lanes/bank = free (m136)
#define COMPUTE(sel)                                                                   \
    {                                                                                  \
        bf16x8 af[4], bfr[4];                                                          \
        _Pragma("unroll") for (int m = 0; m < 4; m++) {                                \
            int r = m * 16 + l15;                                                      \
            af[m] = *(const bf16x8*)(&smA[sel][r * BK_ + (g ^ ((r >> 1) & 3)) * 8]);   \
        }                                                                              \
        _Pragma("unroll") for (int n = 0; n < 4; n++) {                                \
            int r = n * 16 + l15;                                                      \
            bfr[n] = *(const bf16x8*)(&smB[sel][r * BK_ + (g ^ ((r >> 1) & 3)) * 8]);  \
        }                                                                              \
        _Pragma("unroll") for (int m = 0; m < 4; m++)                                  \
            _Pragma("unroll") for (int n = 0; n < 4; n++)                              \
                acc[m][n] = __builtin_amdgcn_mfma_f32_16x16x32_bf16(af[m], bfr[n],     \
                                                                    acc[m][n], 0, 0, 0); \
    }

    // Self-paced pipeline: stage k+1 (8 loads), wait vmcnt(8) => tile k landed,
    // compute k. No barriers (single wave). "memory" clobber keeps ds_read/gload
    // on the right side of the wait; sched_barrier pins scheduling (rule 18).
    STAGE(0, 0);
    int kk = BK_;
#pragma unroll 1
    for (int t = 0; t < NT_ - 1; t++) {
        STAGE((t + 1) & 1, kk);
        asm volatile("s_waitcnt vmcnt(8)" ::: "memory");
        __builtin_amdgcn_sched_barrier(0);
        COMPUTE(t & 1);
        kk += BK_;
    }
    asm volatile("s_waitcnt vmcnt(0)" ::: "memory");
    __builtin_amdgcn_sched_barrier(0);
    COMPUTE((NT_ - 1) & 1);
    __builtin_amdgcn_sched_barrier(0);

    // epilogue: C/D layout col=lane&15, row=(lane>>4)*4+reg  [m89/m91 verified]
    float mq[4];
    int colv[4];
#pragma unroll
    for (int n = 0; n < 4; n++) {
        colv[n] = bc * 64 + n * 16 + l15;
        mq[n] = musq[colv[n]];  // pads hold 1e30 -> exp underflows to exactly 0
    }
    float rp[4][4];
#pragma unroll
    for (int m = 0; m < 4; m++)
#pragma unroll
        for (int j = 0; j < 4; j++) rp[m][j] = 0.f;
    float sSum = 0.f;
#pragma unroll
    for (int m = 0; m < 4; m++)
#pragma unroll
        for (int n = 0; n < 4; n++) {
            const bool valid = colv[n] < C_;
#pragma unroll
            for (int j = 0; j < 4; j++) {
                float s = acc[m][n][j];
                if (valid) sSum += s;
                rp[m][j] += __expf(s - 0.5f * mq[n]);
            }
        }
#pragma unroll
    for (int m = 0; m < 4; m++)
#pragma unroll
        for (int j = 0; j < 4; j++) {
            float v = rp[m][j];
            v += __shfl_xor(v, 1, 64);
            v += __shfl_xor(v, 2, 64);
            v += __shfl_xor(v, 4, 64);
            v += __shfl_xor(v, 8, 64);
            if (l15 == 0) atomicAdd(&row_sumexp[br * 64 + m * 16 + g * 4 + j], v);
        }
    sSum = waveReduce(sSum);
    if (lane == 0) atomicAdd(sS, sSum);
}

// ---- finalize: per-row LSE -> nll_joint/nll_class/cat_ce means + analytic mean(logits)
__global__ __launch_bounds__(256) void finalize(const float* __restrict__ rs,
                                                const float* __restrict__ zsq,
                                                const float* __restrict__ musq,
                                                const float* __restrict__ zzlab,
                                                const float* __restrict__ jac,
                                                const float* __restrict__ sS,
                                                float* __restrict__ out) {
    const int t = threadIdx.x;
    const float logC = logf((float)C_);
    const float invD = 1.0f / (float)D_;
    float snj = 0.f, snc = 0.f, scc = 0.f, szsq = 0.f;
    for (int r = t; r < B_; r += 256) {
        float lse = logf(rs[r]) - 0.5f * zsq[r] - logC;
        float nj = (-lse - jac[r]) * invD;
        float nc = (0.5f * zzlab[r] - jac[r]) * invD;
        snj += nj;
        snc += nc;
        scc += (nc - nj);
        szsq += zsq[r];
    }
    float smu = 0.f;
    for (int c = t; c < C_; c += 256) smu += musq[c];
    float vals[5] = {snj, snc, scc, szsq, smu};
    __shared__ float red[5][4];
#pragma unroll
    for (int i = 0; i < 5; i++) {
        float v = waveReduce(vals[i]);
        if ((t & 63) == 0) red[i][t >> 6] = v;
    }
    __syncthreads();
    if (t == 0) {
        float s[5];
#pragma unroll
        for (int i = 0; i < 5; i++) s[i] = red[i][0] + red[i][1] + red[i][2] + red[i][3];
        const float SNJ = s[0], SNC = s[1], SCC = s[2], SZSQ = s[3], SMU = s[4];
        float meanS = sS[0] / ((float)B_ * (float)C_);
        out[0] = SNJ / (float)B_;                                                  // mean nll_joint
        out[1] = -0.5f * (SZSQ / (float)B_) - 0.5f * (SMU / (float)C_) + meanS;    // mean logits
        out[2] = SNC / (float)B_;                                                  // mean nll_class
        out[3] = SCC * (float)D_ / (float)B_;                                      // mean cat_ce
    }
}

extern "C" void kernel_launch(void* const* d_in, const int* in_sizes, int n_in,
                              void* d_out, int out_size, void* d_ws, size_t ws_size,
                              hipStream_t stream) {
    const float* z = (const float*)d_in[0];
    const float* mu = (const float*)d_in[1];
    const float* jac = (const float*)d_in[2];
    const float* y = (const float*)d_in[3];
    float* out = (float*)d_out;

    char* ws = (char*)d_ws;
    const size_t OFF_ZB = 0;                               // 8192*2048*2 = 33554432
    const size_t OFF_MUB = 33554432;                       // 1024*2048*2 =  4194304
    const size_t OFF_ZSQ = OFF_MUB + 4194304;              // 8192*4
    const size_t OFF_MUSQ = OFF_ZSQ + 32768;               // 1024*4
    const size_t OFF_ZZL = OFF_MUSQ + 4096;                // 8192*4
    const size_t OFF_RS = OFF_ZZL + 32768;                 // 8192*4
    const size_t OFF_SS = OFF_RS + 32768;                  // 4 (+pad)
    ushort_t* zb = (ushort_t*)(ws + OFF_ZB);
    ushort_t* mub = (ushort_t*)(ws + OFF_MUB);
    float* zsq = (float*)(ws + OFF_ZSQ);
    float* musq = (float*)(ws + OFF_MUSQ);
    float* zzlab = (float*)(ws + OFF_ZZL);
    float* rs = (float*)(ws + OFF_RS);
    float* sS = (float*)(ws + OFF_SS);

    // 3 graph nodes total (was 6): prep_all (incl. rs/sS zeroing) -> gemm -> finalize
    prep_all<<<CP_ + B_, 256, 0, stream>>>(z, mu, y, zb, mub, musq, zsq, zzlab, rs, sS);
    gemm_lse<<<2048, 64, 0, stream>>>(zb, mub, musq, rs, sS);
    finalize<<<1, 256, 0, stream>>>(rs, zsq, musq, zzlab, jac, sS, out);
}

// Round 6
// 210.562 us; speedup vs baseline: 1.0532x; 1.0532x over previous
//
#include <hip/hip_runtime.h>

typedef unsigned short ushort_t;
typedef unsigned int uint_t;

#define B_ 8192
#define C_ 1000
#define CP_ 1024   /* padded classes */
#define D_ 2048

#define BM_ 256
#define BN_ 128
#define BKT_ 64
#define NKT_ (D_ / BKT_)   /* 32 K-tiles */

typedef short bf16x8 __attribute__((ext_vector_type(8)));
typedef float f32x4 __attribute__((ext_vector_type(4)));

typedef const __attribute__((address_space(1))) void* as1_cvp;
typedef __attribute__((address_space(3))) void* as3_vp;
#define GLOAD16(gp, lp) __builtin_amdgcn_global_load_lds((as1_cvp)(gp), (as3_vp)(lp), 16, 0, 0)

__device__ __forceinline__ ushort_t f2bf(float f) {
    uint_t x = __float_as_uint(f);
    uint_t r = (x + 0x7fffu + ((x >> 16) & 1u)) >> 16;
    return (ushort_t)r;
}

__device__ __forceinline__ float waveReduce(float v) {
#pragma unroll
    for (int o = 32; o; o >>= 1) v += __shfl_xor(v, o, 64);
    return v;
}

// ---- prep_all: ONE dispatch for all preprocessing (unchanged from R5, passed).
__global__ __launch_bounds__(256) void prep_all(const float* __restrict__ z,
                                                const float* __restrict__ mu,
                                                const float* __restrict__ y,
                                                ushort_t* __restrict__ zb,
                                                ushort_t* __restrict__ mub,
                                                float* __restrict__ musq,
                                                float* __restrict__ zsq,
                                                float* __restrict__ zzlab,
                                                float* __restrict__ rs,
                                                float* __restrict__ sS) {
    const int t = threadIdx.x;
    __shared__ float sb[3][4];
    __shared__ int slab;

    if (blockIdx.x < CP_) {
        const int c = blockIdx.x;
        if (t < 8) rs[c * 8 + t] = 0.f;
        if (c == 0 && t == 0) *sS = 0.f;
        if (c < C_) {
            const float4* mr = (const float4*)(mu + (size_t)c * D_);
            float4 a = mr[t * 2];
            float4 b = mr[t * 2 + 1];
            float vals[8] = {a.x, a.y, a.z, a.w, b.x, b.y, b.z, b.w};
            ushort_t u[8];
            float ss = 0.f;
#pragma unroll
            for (int i = 0; i < 8; i++) { ss += vals[i] * vals[i]; u[i] = f2bf(vals[i]); }
            *(uint4*)(mub + (size_t)c * D_ + t * 8) = *(const uint4*)u;
            ss = waveReduce(ss);
            if ((t & 63) == 0) sb[0][t >> 6] = ss;
            __syncthreads();
            if (t == 0) musq[c] = sb[0][0] + sb[0][1] + sb[0][2] + sb[0][3];
        } else {
            uint4 zero4 = {0, 0, 0, 0};
            *(uint4*)(mub + (size_t)c * D_ + t * 8) = zero4;
            if (t == 0) musq[c] = 1e30f;  // exp(S - 0.5e30) == 0 -> pads vanish from LSE
        }
        return;
    }

    const int r = blockIdx.x - CP_;
    if (t < C_ / 4) {
        float4 v = ((const float4*)(y + (size_t)r * C_))[t];
        int idx = -1;
        if (v.x > 0.5f) idx = t * 4 + 0;
        if (v.y > 0.5f) idx = t * 4 + 1;
        if (v.z > 0.5f) idx = t * 4 + 2;
        if (v.w > 0.5f) idx = t * 4 + 3;
        if (idx >= 0) slab = idx;  // exactly one thread writes
    }
    __syncthreads();
    const int L = slab;
    const float4* zr = (const float4*)(z + (size_t)r * D_);
    const float4* mr = (const float4*)(mu + (size_t)L * D_);
    float4 a = zr[t * 2];
    float4 b = zr[t * 2 + 1];
    float4 ma = mr[t * 2];
    float4 mb = mr[t * 2 + 1];
    float vals[8] = {a.x, a.y, a.z, a.w, b.x, b.y, b.z, b.w};
    float mv[8] = {ma.x, ma.y, ma.z, ma.w, mb.x, mb.y, mb.z, mb.w};
    ushort_t u[8];
    float ss = 0.f, dot = 0.f, msq = 0.f;
#pragma unroll
    for (int i = 0; i < 8; i++) {
        ss += vals[i] * vals[i];
        dot += vals[i] * mv[i];
        msq += mv[i] * mv[i];
        u[i] = f2bf(vals[i]);
    }
    *(uint4*)(zb + (size_t)r * D_ + t * 8) = *(const uint4*)u;
    ss = waveReduce(ss);
    dot = waveReduce(dot);
    msq = waveReduce(msq);
    if ((t & 63) == 0) { sb[0][t >> 6] = ss; sb[1][t >> 6] = dot; sb[2][t >> 6] = msq; }
    __syncthreads();
    if (t == 0) {
        float SS = sb[0][0] + sb[0][1] + sb[0][2] + sb[0][3];
        float DT = sb[1][0] + sb[1][1] + sb[1][2] + sb[1][3];
        float MQ = sb[2][0] + sb[2][1] + sb[2][2] + sb[2][3];
        zsq[r] = SS;
        zzlab[r] = SS + MQ - 2.f * DT;
    }
}

// ---- gemm_lse: 256x128 tile, BK=64, 8 waves (4x2), RING-3 LDS (144KB),
//      prefetch distance 2, COUNTED s_waitcnt vmcnt(6) + raw s_barrier (no drain):
//      loads stay in flight across barriers (T4). Per iter:
//        wait vmcnt(6) -> barrier -> compute kt -> barrier -> issue STAGE(kt+2).
//      Swizzle: read slot=(ks*4+g)^(r&7); staging source inverse-swizzled (rule 21).
//      Fused epilogue: row_sumexp += sum_c exp(S - 0.5*musq); sS += sum_{c<1000} S.
__global__ __launch_bounds__(512, 1) void gemm_lse(const ushort_t* __restrict__ zb,
                                                   const ushort_t* __restrict__ mub,
                                                   const float* __restrict__ musq,
                                                   float* __restrict__ row_sumexp,
                                                   float* __restrict__ sS) {
    // per ring buffer: A = 256x64 ushort (32KB) at [0,16384), B = 128x64 (16KB) at [16384,24576)
    __shared__ ushort_t sm[3][24576];   // 144KB total -> 1 block/CU
    const int tid = threadIdx.x;
    const int lane = tid & 63;
    const int w = tid >> 6;             // 0..7
    const int wr = w >> 1, wc = w & 1;  // 4x2 wave grid; wave-tile 64x64
    const int l15 = lane & 15;
    const int g = lane >> 4;

    // XCD-aware bijective remap: 256 blocks = 32 br x 8 bc; each XCD owns 4 br panels.
    const int f = blockIdx.x;
    const int xcd = f & 7;
    const int idx = f >> 3;             // 0..31
    const int br = xcd * 4 + (idx & 3); // 0..31
    const int bc = idx >> 2;            // 0..7

    f32x4 acc[4][4];
#pragma unroll
    for (int m = 0; m < 4; m++)
#pragma unroll
        for (int n = 0; n < 4; n++)
#pragma unroll
            for (int j = 0; j < 4; j++) acc[m][n][j] = 0.f;

    const ushort_t* gA = zb + (size_t)br * BM_ * D_;
    const ushort_t* gB = mub + (size_t)bc * BN_ * D_;

    // Staging maps: A = 2048 gload16 (4 per thread), B = 1024 (2 per thread).
    // LDS dest linear in ldi (wave-uniform base + lane*16, m104-safe);
    // global source slot inverse-swizzled: s = slot' ^ (row&7).
    int sa_r[4], sa_s[4];
#pragma unroll
    for (int it = 0; it < 4; it++) {
        int ldi = it * 512 + tid;
        sa_r[it] = ldi >> 3;
        sa_s[it] = (ldi & 7) ^ (sa_r[it] & 7);
    }
    int sb_r[2], sb_s[2];
#pragma unroll
    for (int it = 0; it < 2; it++) {
        int ldj = it * 512 + tid;
        sb_r[it] = ldj >> 3;
        sb_s[it] = (ldj & 7) ^ (sb_r[it] & 7);
    }

    // 6 gload16 per thread per K-tile (4 A + 2 B)
#define STAGE(bufi, kk)                                                                \
    {                                                                                  \
        _Pragma("unroll") for (int it = 0; it < 4; it++) {                             \
            GLOAD16(gA + (size_t)sa_r[it] * D_ + (kk) + sa_s[it] * 8,                  \
                    &sm[bufi][(it * 512 + tid) * 8]);                                  \
        }                                                                              \
        _Pragma("unroll") for (int it = 0; it < 2; it++) {                             \
            GLOAD16(gB + (size_t)sb_r[it] * D_ + (kk) + sb_s[it] * 8,                  \
                    &sm[bufi][16384 + (it * 512 + tid) * 8]);                          \
        }                                                                              \
    }

    // 16 ds_read_b128 + 32 MFMA per wave per K-tile; compiler auto-inserts lgkmcnt.
#define COMPUTE(bufi)                                                                  \
    {                                                                                  \
        _Pragma("unroll") for (int ks = 0; ks < 2; ks++) {                             \
            bf16x8 af[4], bfr[4];                                                      \
            _Pragma("unroll") for (int m = 0; m < 4; m++) {                            \
                int r = wr * 64 + m * 16 + l15;                                        \
                int slot = (ks * 4 + g) ^ (r & 7);                                     \
                af[m] = *(const bf16x8*)(&sm[bufi][r * 64 + slot * 8]);                \
            }                                                                          \
            _Pragma("unroll") for (int n = 0; n < 4; n++) {                            \
                int r = wc * 64 + n * 16 + l15;                                        \
                int slot = (ks * 4 + g) ^ (r & 7);                                     \
                bfr[n] = *(const bf16x8*)(&sm[bufi][16384 + r * 64 + slot * 8]);       \
            }                                                                          \
            __builtin_amdgcn_s_setprio(1);                                             \
            _Pragma("unroll") for (int m = 0; m < 4; m++)                              \
                _Pragma("unroll") for (int n = 0; n < 4; n++)                          \
                    acc[m][n] = __builtin_amdgcn_mfma_f32_16x16x32_bf16(               \
                        af[m], bfr[n], acc[m][n], 0, 0, 0);                            \
            __builtin_amdgcn_s_setprio(0);                                             \
        }                                                                              \
    }

    // prologue: tiles 0,1 in flight (12 loads/wave outstanding)
    STAGE(0, 0);
    STAGE(1, BKT_);
#pragma unroll 1
    for (int kt = 0; kt < NKT_ - 1; kt++) {
        asm volatile("s_waitcnt vmcnt(6)" ::: "memory");   // own portion of tile kt landed
        __builtin_amdgcn_sched_barrier(0);
        __builtin_amdgcn_s_barrier();                      // ALL waves' portions landed
        __builtin_amdgcn_sched_barrier(0);
        COMPUTE(kt % 3);
        __builtin_amdgcn_sched_barrier(0);
        __builtin_amdgcn_s_barrier();                      // all reads of recycled buf done
        __builtin_amdgcn_sched_barrier(0);
        if (kt + 2 < NKT_) STAGE((kt + 2) % 3, (kt + 2) * BKT_);
    }
    asm volatile("s_waitcnt vmcnt(0)" ::: "memory");       // last tile landed
    __builtin_amdgcn_sched_barrier(0);
    __builtin_amdgcn_s_barrier();
    __builtin_amdgcn_sched_barrier(0);
    COMPUTE((NKT_ - 1) % 3);

    // epilogue: C/D layout col=lane&15, row=(lane>>4)*4+reg  [m89/m91 verified]
    float mq[4];
    int colv[4];
#pragma unroll
    for (int n = 0; n < 4; n++) {
        colv[n] = bc * BN_ + wc * 64 + n * 16 + l15;
        mq[n] = musq[colv[n]];  // pads hold 1e30 -> exp underflows to exactly 0
    }
    float rp[4][4];
#pragma unroll
    for (int m = 0; m < 4; m++)
#pragma unroll
        for (int j = 0; j < 4; j++) rp[m][j] = 0.f;
    float sSum = 0.f;
#pragma unroll
    for (int m = 0; m < 4; m++)
#pragma unroll
        for (int n = 0; n < 4; n++) {
            const bool valid = colv[n] < C_;
#pragma unroll
            for (int j = 0; j < 4; j++) {
                float s = acc[m][n][j];
                if (valid) sSum += s;
                rp[m][j] += __expf(s - 0.5f * mq[n]);
            }
        }
#pragma unroll
    for (int m = 0; m < 4; m++)
#pragma unroll
        for (int j = 0; j < 4; j++) {
            float v = rp[m][j];
            v += __shfl_xor(v, 1, 64);
            v += __shfl_xor(v, 2, 64);
            v += __shfl_xor(v, 4, 64);
            v += __shfl_xor(v, 8, 64);
            if (l15 == 0) {
                int grow = br * BM_ + wr * 64 + m * 16 + g * 4 + j;
                atomicAdd(&row_sumexp[grow], v);
            }
        }
    sSum = waveReduce(sSum);
    if (lane == 0) atomicAdd(sS, sSum);
}

// ---- finalize: per-row LSE -> nll_joint/nll_class/cat_ce means + analytic mean(logits)
__global__ __launch_bounds__(256) void finalize(const float* __restrict__ rs,
                                                const float* __restrict__ zsq,
                                                const float* __restrict__ musq,
                                                const float* __restrict__ zzlab,
                                                const float* __restrict__ jac,
                                                const float* __restrict__ sS,
                                                float* __restrict__ out) {
    const int t = threadIdx.x;
    const float logC = logf((float)C_);
    const float invD = 1.0f / (float)D_;
    float snj = 0.f, snc = 0.f, scc = 0.f, szsq = 0.f;
    for (int r = t; r < B_; r += 256) {
        float lse = logf(rs[r]) - 0.5f * zsq[r] - logC;
        float nj = (-lse - jac[r]) * invD;
        float nc = (0.5f * zzlab[r] - jac[r]) * invD;
        snj += nj;
        snc += nc;
        scc += (nc - nj);
        szsq += zsq[r];
    }
    float smu = 0.f;
    for (int c = t; c < C_; c += 256) smu += musq[c];
    float vals[5] = {snj, snc, scc, szsq, smu};
    __shared__ float red[5][4];
#pragma unroll
    for (int i = 0; i < 5; i++) {
        float v = waveReduce(vals[i]);
        if ((t & 63) == 0) red[i][t >> 6] = v;
    }
    __syncthreads();
    if (t == 0) {
        float s[5];
#pragma unroll
        for (int i = 0; i < 5; i++) s[i] = red[i][0] + red[i][1] + red[i][2] + red[i][3];
        const float SNJ = s[0], SNC = s[1], SCC = s[2], SZSQ = s[3], SMU = s[4];
        float meanS = sS[0] / ((float)B_ * (float)C_);
        out[0] = SNJ / (float)B_;                                                  // mean nll_joint
        out[1] = -0.5f * (SZSQ / (float)B_) - 0.5f * (SMU / (float)C_) + meanS;    // mean logits
        out[2] = SNC / (float)B_;                                                  // mean nll_class
        out[3] = SCC * (float)D_ / (float)B_;                                      // mean cat_ce
    }
}

extern "C" void kernel_launch(void* const* d_in, const int* in_sizes, int n_in,
                              void* d_out, int out_size, void* d_ws, size_t ws_size,
                              hipStream_t stream) {
    const float* z = (const float*)d_in[0];
    const float* mu = (const float*)d_in[1];
    const float* jac = (const float*)d_in[2];
    const float* y = (const float*)d_in[3];
    float* out = (float*)d_out;

    char* ws = (char*)d_ws;
    const size_t OFF_ZB = 0;                               // 8192*2048*2 = 33554432
    const size_t OFF_MUB = 33554432;                       // 1024*2048*2 =  4194304
    const size_t OFF_ZSQ = OFF_MUB + 4194304;              // 8192*4
    const size_t OFF_MUSQ = OFF_ZSQ + 32768;               // 1024*4
    const size_t OFF_ZZL = OFF_MUSQ + 4096;                // 8192*4
    const size_t OFF_RS = OFF_ZZL + 32768;                 // 8192*4
    const size_t OFF_SS = OFF_RS + 32768;                  // 4 (+pad)
    ushort_t* zb = (ushort_t*)(ws + OFF_ZB);
    ushort_t* mub = (ushort_t*)(ws + OFF_MUB);
    float* zsq = (float*)(ws + OFF_ZSQ);
    float* musq = (float*)(ws + OFF_MUSQ);
    float* zzlab = (float*)(ws + OFF_ZZL);
    float* rs = (float*)(ws + OFF_RS);
    float* sS = (float*)(ws + OFF_SS);

    prep_all<<<CP_ + B_, 256, 0, stream>>>(z, mu, y, zb, mub, musq, zsq, zzlab, rs, sS);
    gemm_lse<<<256, 512, 0, stream>>>(zb, mub, musq, rs, sS);
    finalize<<<1, 256, 0, stream>>>(rs, zsq, musq, zzlab, jac, sS, out);
}